// Round 4
// baseline (340.642 us; speedup 1.0000x reference)
//
#include <hip/hip_runtime.h>
#include <math.h>

#define BB 8
#define CC 96
#define HH 256
#define WW 256
#define HW (HH*WW)

typedef unsigned long long u64;
typedef float f32x4 __attribute__((ext_vector_type(4)));

// ---------------- channel mean: x[B,C,H,W] -> m[B,H,W] ----------------
// block = (b, tile of 64 float4s); 4 waves, each sums a 24-channel chunk; f64 LDS combine.
__global__ void k_mean(const float* __restrict__ x, float* __restrict__ m) {
    int blk = blockIdx.x;                 // b*256 + tile
    int b = blk >> 8, tile = blk & 255;
    int wv = threadIdx.x >> 6, ln = threadIdx.x & 63;
    int hw4 = tile * 64 + ln;             // float4 index within image
    const int per = HW / 4;               // 16384
    const float4* xb = reinterpret_cast<const float4*>(x)
                     + ((size_t)b * CC + wv * 24) * per + hw4;
    double a0 = 0, a1 = 0, a2 = 0, a3 = 0;
#pragma unroll
    for (int c = 0; c < 24; ++c) {
        float4 v = xb[(size_t)c * per];
        a0 += (double)v.x; a1 += (double)v.y; a2 += (double)v.z; a3 += (double)v.w;
    }
    __shared__ double sbuf[4][4][64];
    sbuf[wv][0][ln] = a0; sbuf[wv][1][ln] = a1;
    sbuf[wv][2][ln] = a2; sbuf[wv][3][ln] = a3;
    __syncthreads();
    if (wv == 0) {
        double r0 = sbuf[0][0][ln] + sbuf[1][0][ln] + sbuf[2][0][ln] + sbuf[3][0][ln];
        double r1 = sbuf[0][1][ln] + sbuf[1][1][ln] + sbuf[2][1][ln] + sbuf[3][1][ln];
        double r2 = sbuf[0][2][ln] + sbuf[1][2][ln] + sbuf[2][2][ln] + sbuf[3][2][ln];
        double r3 = sbuf[0][3][ln] + sbuf[1][3][ln] + sbuf[2][3][ln] + sbuf[3][3][ln];
        float4 o;
        o.x = (float)(r0 / 96.0); o.y = (float)(r1 / 96.0);
        o.z = (float)(r2 / 96.0); o.w = (float)(r3 / 96.0);
        reinterpret_cast<float4*>(m)[(size_t)b * per + hw4] = o;
    }
}

// ---------------- fused middle: sobel -> minmax -> c/adj/part -> base -> traversal -> scale
// one block per image; adj + visit masks live in LDS; mag round-trips via L2.
#define SETBIT(j) do { int _j = (j); \
    if (_j < 64) m0 |= 1ull << _j; \
    else if (_j < 128) m1 |= 1ull << (_j - 64); \
    else if (_j < 192) m2 |= 1ull << (_j - 128); \
    else m3 |= 1ull << (_j - 192); } while (0)

__global__ __launch_bounds__(1024)
void k_middle(const float* __restrict__ m, float* __restrict__ mag,
              float* __restrict__ scale) {
    __shared__ signed char adj_s[HW];          // 64 KB
    __shared__ u64 mask_s[1024][4];            // 32 KB
    __shared__ float part_s[256][2];           // 2 KB
    __shared__ float partial_s[256][4];        // 4 KB
    __shared__ double sd[4][128];              // 4 KB
    __shared__ float red_mn[16], red_mx[16];
    __shared__ float smn_f, smx_f;
    __shared__ int sbs[4];

    int b = blockIdx.x, tid = threadIdx.x;
    const float* mb = m + (size_t)b * HW;
    float* gb = mag + (size_t)b * HW;
    int wv = tid >> 6, ln = tid & 63;

    auto at = [&](int hh, int ww) -> float {
        if (hh < 0 || hh >= HH || ww < 0 || ww >= WW) return 0.0f;
        return mb[hh * WW + ww];
    };

    // ---- phase 1: sobel magnitude + per-image min/max (order-exact reduce) ----
    float lmn = __builtin_inff(), lmx = -__builtin_inff();
    for (int p = 0; p < 64; ++p) {
        int idx = p * 1024 + tid;
        int h = idx >> 8, w = idx & 255;
        float a00 = at(h - 1, w - 1), a01 = at(h - 1, w), a02 = at(h - 1, w + 1);
        float a10 = at(h, w - 1),                         a12 = at(h, w + 1);
        float a20 = at(h + 1, w - 1), a21 = at(h + 1, w), a22 = at(h + 1, w + 1);
        float gx = a00 - a02 + 2.0f * a10 - 2.0f * a12 + a20 - a22;
        float gy = a00 + 2.0f * a01 + a02 - a20 - 2.0f * a21 - a22;
        float mg = sqrtf(gx * gx + gy * gy + 1e-6f);
        gb[idx] = mg;
        lmn = fminf(lmn, mg); lmx = fmaxf(lmx, mg);
    }
    for (int off = 32; off; off >>= 1) {
        lmn = fminf(lmn, __shfl_down(lmn, off));
        lmx = fmaxf(lmx, __shfl_down(lmx, off));
    }
    if (ln == 0) { red_mn[wv] = lmn; red_mx[wv] = lmx; }
    __syncthreads();
    if (tid == 0) {
        float a = red_mn[0], c2 = red_mx[0];
        for (int i = 1; i < 16; ++i) { a = fminf(a, red_mn[i]); c2 = fmaxf(c2, red_mx[i]); }
        smn_f = a; smx_f = c2;
    }
    __syncthreads();
    float mn = smn_f, mx = smx_f, rng = mx - mn;
    auto cat = [&](int hh, int ww) -> float {
        if (hh < 0 || hh >= HH || ww < 0 || ww >= WW) return 0.0f;
        float mg = gb[hh * WW + ww];
        return (rng > 0.0f) ? (mg - mn) / (rng + 1e-6f) : 0.0f;
    };

    // ---- phase 2: c (recompute), half-row partials (bit-identical wave trees), adj ----
    int g = tid >> 8, w2 = tid & 255;      // row group / column; replays old 256-thread block
    const float w9 = 1.0f / 9.0f;
    for (int p = 0; p < 64; ++p) {
        int h = p * 4 + g;
        float cc = cat(h, w2);
        float r = cc;
        for (int off = 32; off; off >>= 1) r += __shfl_down(r, off);
        if (ln == 0) partial_s[h][w2 >> 6] = r;   // one wave-sum slot per (row, quarter)
        float acc = 0.0f;
        acc = fmaf(cat(h - 1, w2 - 1), w9, acc);
        acc = fmaf(cat(h - 1, w2    ), w9, acc);
        acc = fmaf(cat(h - 1, w2 + 1), w9, acc);
        acc = fmaf(cat(h    , w2 - 1), w9, acc);
        acc = fmaf(cc,                w9, acc);
        acc = fmaf(cat(h    , w2 + 1), w9, acc);
        acc = fmaf(cat(h + 1, w2 - 1), w9, acc);
        acc = fmaf(cat(h + 1, w2    ), w9, acc);
        acc = fmaf(cat(h + 1, w2 + 1), w9, acc);
        float sg = 1.0f / (1.0f + expf(-5.0f * (acc - 0.5f)));
        adj_s[h * 256 + w2] = (signed char)(int)rintf(sg * 2.0f - 1.0f);
    }
    __syncthreads();
    if (tid < 512) {                       // part[row][col] = s[2c]+s[2c+1]  (same as before)
        int row = tid >> 1, col = tid & 1;
        part_s[row][col] = partial_s[row][2 * col] + partial_s[row][2 * col + 1];
    }
    __syncthreads();

    // ---- phase 3: base per direction (f64 tree, str=64..1, same order) ----
    if (tid < 512) {
        int d = tid >> 7, t = tid & 127;
        int hlo = (d >> 1) ? 128 : 0, col = d & 1;
        sd[d][t] = (double)part_s[hlo + t][col];
    }
    __syncthreads();
    for (int str = 64; str > 0; str >>= 1) {
        if (tid < 512) {
            int d = tid >> 7, t = tid & 127;
            if (t < str) sd[d][t] += sd[d][t + str];
        }
        __syncthreads();
    }
    if (tid < 4) {
        float rc = (float)(sd[tid][0] / 16384.0);
        float sig = 1.0f / (1.0f + expf(-5.0f * (rc - 0.5f)));
        float bsf = 5.0f - sig * 4.0f;
        bsf = fminf(fmaxf(bsf, 1.0f), 5.0f);
        sbs[tid] = (int)rintf(bsf);
    }
    __syncthreads();

    // ---- phase 4: 4-direction traversal, adj from LDS ----
    {
        int dir = tid >> 8, rr = tid & 255;
        int bs = sbs[dir];
        u64 m0 = 0, m1 = 0, m2 = 0, m3 = 0;
        if (dir == 0) {
            int j = 0;
            while (j < WW) { SETBIT(j);
                int st = bs + (int)adj_s[rr * 256 + j];
                st = st < 1 ? 1 : (st > 5 ? 5 : st); j += st; }
        } else if (dir == 1) {
            int j = WW - 1;
            while (j >= 0) { SETBIT(j);
                int st = bs + (int)adj_s[rr * 256 + j];
                st = st < 1 ? 1 : (st > 5 ? 5 : st); j -= st; }
        } else if (dir == 2) {
            int j = 0;
            while (j < HH) { SETBIT(j);
                int st = bs + (int)adj_s[j * 256 + rr];
                st = st < 1 ? 1 : (st > 5 ? 5 : st); j += st; }
        } else {
            int j = HH - 1;
            while (j >= 0) { SETBIT(j);
                int st = bs + (int)adj_s[j * 256 + rr];
                st = st < 1 ? 1 : (st > 5 ? 5 : st); j -= st; }
        }
        mask_s[tid][0] = m0; mask_s[tid][1] = m1;
        mask_s[tid][2] = m2; mask_s[tid][3] = m3;
    }
    __syncthreads();

    // ---- phase 5: visit count -> scale ----
    for (int p = 0; p < 64; ++p) {
        int idx = p * 1024 + tid;
        int h = idx >> 8, w = idx & 255;
        const u64* q0 = mask_s[0 * 256 + h];
        const u64* q1 = mask_s[1 * 256 + h];
        const u64* q2 = mask_s[2 * 256 + w];
        const u64* q3 = mask_s[3 * 256 + w];
        int v = (int)((q0[w >> 6] >> (w & 63)) & 1ull)
              + (int)((q1[w >> 6] >> (w & 63)) & 1ull)
              + (int)((q2[h >> 6] >> (h & 63)) & 1ull)
              + (int)((q3[h >> 6] >> (h & 63)) & 1ull);
        float fV = (float)v;
        scale[(size_t)b * HW + idx] = fV / (fV + 1e-6f);
    }
}

// ---------------- output: out = x * scale (broadcast over C), nontemporal stores ----------------
__global__ void k_out(const float* __restrict__ x, const float* __restrict__ scale,
                      float* __restrict__ out) {
    const int per_img4 = CC * HW / 4;     // 1572864
    const int hw4n = HW / 4;              // 16384 (pow2)
    int i = blockIdx.x * blockDim.x + threadIdx.x;   // exact cover of total4
    int b = i / per_img4;
    int hw4 = i & (hw4n - 1);
    f32x4 sv = reinterpret_cast<const f32x4*>(scale)[b * hw4n + hw4];
    f32x4 xv = reinterpret_cast<const f32x4*>(x)[i];
    f32x4 ov = xv * sv;
    __builtin_nontemporal_store(ov, reinterpret_cast<f32x4*>(out) + i);
}

extern "C" void kernel_launch(void* const* d_in, const int* in_sizes, int n_in,
                              void* d_out, int out_size, void* d_ws, size_t ws_size,
                              hipStream_t stream) {
    const float* x = (const float*)d_in[0];
    float* out = (float*)d_out;
    char* ws = (char*)d_ws;

    float* m     = (float*)(ws);                                    // 2 MB
    float* mag   = (float*)(ws + (size_t)2 * 1024 * 1024);          // 2 MB
    float* scale = (float*)(ws + (size_t)4 * 1024 * 1024);          // 2 MB

    k_mean<<<BB * 256, 256, 0, stream>>>(x, m);
    k_middle<<<BB, 1024, 0, stream>>>(m, mag, scale);
    k_out<<<(BB * CC * HW / 4) / 256, 256, 0, stream>>>(x, scale, out);
}

// Round 5
// 302.497 us; speedup vs baseline: 1.1261x; 1.1261x over previous
//
#include <hip/hip_runtime.h>
#include <math.h>

#define BB 8
#define CC 96
#define HH 256
#define WW 256
#define HW (HH*WW)

typedef unsigned long long u64;
typedef float f32x4 __attribute__((ext_vector_type(4)));

// ---------------- channel mean: x[B,C,H,W] -> m[B,H,W]  (+ init min/max) ----------------
// block = (b, tile of 64 float4s); 4 waves, each sums a 24-channel chunk; f64 LDS combine.
__global__ void k_mean(const float* __restrict__ x, float* __restrict__ m,
                       unsigned* __restrict__ mn_u, unsigned* __restrict__ mx_u) {
    if (blockIdx.x == 0 && threadIdx.x < 2 * BB) {
        if (threadIdx.x < BB) mn_u[threadIdx.x] = 0x7f800000u;
        else                  mx_u[threadIdx.x - BB] = 0u;
    }
    int blk = blockIdx.x;                 // b*256 + tile
    int b = blk >> 8, tile = blk & 255;
    int wv = threadIdx.x >> 6, ln = threadIdx.x & 63;
    int hw4 = tile * 64 + ln;             // float4 index within image
    const int per = HW / 4;               // 16384
    const float4* xb = reinterpret_cast<const float4*>(x)
                     + ((size_t)b * CC + wv * 24) * per + hw4;
    double a0 = 0, a1 = 0, a2 = 0, a3 = 0;
#pragma unroll
    for (int c = 0; c < 24; ++c) {
        float4 v = xb[(size_t)c * per];
        a0 += (double)v.x; a1 += (double)v.y; a2 += (double)v.z; a3 += (double)v.w;
    }
    __shared__ double sbuf[4][4][64];
    sbuf[wv][0][ln] = a0; sbuf[wv][1][ln] = a1;
    sbuf[wv][2][ln] = a2; sbuf[wv][3][ln] = a3;
    __syncthreads();
    if (wv == 0) {
        double r0 = sbuf[0][0][ln] + sbuf[1][0][ln] + sbuf[2][0][ln] + sbuf[3][0][ln];
        double r1 = sbuf[0][1][ln] + sbuf[1][1][ln] + sbuf[2][1][ln] + sbuf[3][1][ln];
        double r2 = sbuf[0][2][ln] + sbuf[1][2][ln] + sbuf[2][2][ln] + sbuf[3][2][ln];
        double r3 = sbuf[0][3][ln] + sbuf[1][3][ln] + sbuf[2][3][ln] + sbuf[3][3][ln];
        float4 o;
        o.x = (float)(r0 / 96.0); o.y = (float)(r1 / 96.0);
        o.z = (float)(r2 / 96.0); o.w = (float)(r3 / 96.0);
        reinterpret_cast<float4*>(m)[(size_t)b * per + hw4] = o;
    }
}

// ---------------- sobel magnitude + per-image min/max ----------------
__global__ void k_sobel(const float* __restrict__ m, float* __restrict__ mag,
                        unsigned* mn_u, unsigned* mx_u) {
    int row = blockIdx.x;            // b*HH + h  (one row per block)
    int b = row >> 8, h = row & 255, w = threadIdx.x;
    const float* mb = m + (size_t)b * HW;
    auto at = [&](int hh, int ww) -> float {
        if (hh < 0 || hh >= HH || ww < 0 || ww >= WW) return 0.0f;
        return mb[hh * WW + ww];
    };
    float a00 = at(h - 1, w - 1), a01 = at(h - 1, w), a02 = at(h - 1, w + 1);
    float a10 = at(h, w - 1),                         a12 = at(h, w + 1);
    float a20 = at(h + 1, w - 1), a21 = at(h + 1, w), a22 = at(h + 1, w + 1);
    float gx = a00 - a02 + 2.0f * a10 - 2.0f * a12 + a20 - a22;
    float gy = a00 + 2.0f * a01 + a02 - a20 - 2.0f * a21 - a22;
    float mg = sqrtf(gx * gx + gy * gy + 1e-6f);
    mag[row * WW + w] = mg;

    float lmn = mg, lmx = mg;
    for (int off = 32; off; off >>= 1) {
        lmn = fminf(lmn, __shfl_down(lmn, off));
        lmx = fmaxf(lmx, __shfl_down(lmx, off));
    }
    __shared__ float smn[4], smx[4];
    int wv = threadIdx.x >> 6, ln = threadIdx.x & 63;
    if (ln == 0) { smn[wv] = lmn; smx[wv] = lmx; }
    __syncthreads();
    if (threadIdx.x == 0) {
        float bmn = fminf(fminf(smn[0], smn[1]), fminf(smn[2], smn[3]));
        float bmx = fmaxf(fmaxf(smx[0], smx[1]), fmaxf(smx[2], smx[3]));
        atomicMin(&mn_u[b], __float_as_uint(bmn));   // mg > 0 -> uint order == float order
        atomicMax(&mx_u[b], __float_as_uint(bmx));
    }
}

// ---------------- fused: normalize (recompute per neighbor) -> adj + part ----------------
__global__ void k_adjpart(const float* __restrict__ mag, const unsigned* __restrict__ mn_u,
                          const unsigned* __restrict__ mx_u, signed char* __restrict__ adj,
                          float* __restrict__ part) {
    int row = blockIdx.x;            // b*HH + h
    int b = row >> 8, h = row & 255, w = threadIdx.x;
    float mn = __uint_as_float(mn_u[b]);
    float mx = __uint_as_float(mx_u[b]);
    float rng = mx - mn;
    const float* gb = mag + (size_t)b * HW;
    auto cat = [&](int hh, int ww) -> float {
        if (hh < 0 || hh >= HH || ww < 0 || ww >= WW) return 0.0f;
        float mg = gb[hh * WW + ww];
        return (rng > 0.0f) ? (mg - mn) / (rng + 1e-6f) : 0.0f;
    };
    float cc = cat(h, w);

    float r = cc;
    for (int off = 32; off; off >>= 1) r += __shfl_down(r, off);
    __shared__ float s[4];
    int wv = threadIdx.x >> 6, ln = threadIdx.x & 63;
    if (ln == 0) s[wv] = r;
    __syncthreads();
    if (threadIdx.x == 0) {
        part[row * 2 + 0] = s[0] + s[1];   // w in [0,128)
        part[row * 2 + 1] = s[2] + s[3];   // w in [128,256)
    }

    const float w9 = 1.0f / 9.0f;
    float acc = 0.0f;
    acc = fmaf(cat(h - 1, w - 1), w9, acc);
    acc = fmaf(cat(h - 1, w    ), w9, acc);
    acc = fmaf(cat(h - 1, w + 1), w9, acc);
    acc = fmaf(cat(h    , w - 1), w9, acc);
    acc = fmaf(cc,               w9, acc);
    acc = fmaf(cat(h    , w + 1), w9, acc);
    acc = fmaf(cat(h + 1, w - 1), w9, acc);
    acc = fmaf(cat(h + 1, w    ), w9, acc);
    acc = fmaf(cat(h + 1, w + 1), w9, acc);
    float sg = 1.0f / (1.0f + expf(-5.0f * (acc - 0.5f)));
    adj[row * WW + w] = (signed char)(int)rintf(sg * 2.0f - 1.0f);
}

// ---------------- fused base + 4-direction adaptive traversal -> bitmasks ----------------
#define SETBIT(j) do { int _j = (j); \
    if (_j < 64) m0 |= 1ull << _j; \
    else if (_j < 128) m1 |= 1ull << (_j - 64); \
    else if (_j < 192) m2 |= 1ull << (_j - 128); \
    else m3 |= 1ull << (_j - 192); } while (0)

__global__ void k_travbase(const signed char* __restrict__ adj, const float* __restrict__ part,
                           u64* __restrict__ masks) {
    int blk = blockIdx.x;                 // 0..31, = dir*8 + b
    int dir = blk >> 3, b = blk & 7;
    int t = threadIdx.x;

    __shared__ double sd[128];
    __shared__ int sbs;
    int hlo = (dir >> 1) ? 128 : 0;
    int col = dir & 1;
    if (t < 128) sd[t] = (double)part[((b << 8) + hlo + t) * 2 + col];
    __syncthreads();
    for (int str = 64; str > 0; str >>= 1) {
        if (t < str) sd[t] += sd[t + str];
        __syncthreads();
    }
    if (t == 0) {
        float rc = (float)(sd[0] / 16384.0);
        float sig = 1.0f / (1.0f + expf(-5.0f * (rc - 0.5f)));
        float bsf = 5.0f - sig * 4.0f;
        bsf = fminf(fmaxf(bsf, 1.0f), 5.0f);
        sbs = (int)rintf(bsf);
    }
    __syncthreads();
    int bs = sbs;

    int r = t;
    const signed char* ab = adj + (size_t)b * HW;
    u64 m0 = 0, m1 = 0, m2 = 0, m3 = 0;
    if (dir == 0) {
        int j = 0;
        while (j < WW) { SETBIT(j);
            int st = bs + (int)ab[r * WW + j];
            st = st < 1 ? 1 : (st > 5 ? 5 : st); j += st; }
    } else if (dir == 1) {
        int j = WW - 1;
        while (j >= 0) { SETBIT(j);
            int st = bs + (int)ab[r * WW + j];
            st = st < 1 ? 1 : (st > 5 ? 5 : st); j -= st; }
    } else if (dir == 2) {
        int j = 0;
        while (j < HH) { SETBIT(j);
            int st = bs + (int)ab[j * WW + r];
            st = st < 1 ? 1 : (st > 5 ? 5 : st); j += st; }
    } else {
        int j = HH - 1;
        while (j >= 0) { SETBIT(j);
            int st = bs + (int)ab[j * WW + r];
            st = st < 1 ? 1 : (st > 5 ? 5 : st); j -= st; }
    }
    u64* o = masks + ((size_t)dir * BB * 256 + (b << 8) + r) * 4;
    o[0] = m0; o[1] = m1; o[2] = m2; o[3] = m3;
}

// ---------------- output: out = x * V/(V+eps), V computed inline from masks ----------------
__global__ void k_out(const float* __restrict__ x, const u64* __restrict__ masks,
                      float* __restrict__ out) {
    const int per_img4 = CC * HW / 4;     // 1572864
    const int hw4n = HW / 4;              // 16384 (pow2)
    int i = blockIdx.x * blockDim.x + threadIdx.x;   // exact cover of total4
    int b = i / per_img4;
    int hw4 = i & (hw4n - 1);
    int h = hw4 >> 6;                     // hw4 = h*64 + w4
    int w0 = (hw4 & 63) << 2;             // first of 4 consecutive w
    int hb = h & 63, hwd = h >> 6;

    // row-direction masks: one word covers w0..w0+3 (w0 is 4-aligned)
    u64 q0 = masks[(((size_t)0 * BB + b) * 256 + h) * 4 + (w0 >> 6)];
    u64 q1 = masks[(((size_t)1 * BB + b) * 256 + h) * 4 + (w0 >> 6)];
    // col-direction masks: per-w word at bit h
    const u64* m2b = masks + (((size_t)2 * BB + b) * 256 + w0) * 4 + hwd;
    const u64* m3b = masks + (((size_t)3 * BB + b) * 256 + w0) * 4 + hwd;
    f32x4 sv;
#pragma unroll
    for (int k = 0; k < 4; ++k) {
        int wbit = (w0 & 63) + k;
        int v = (int)((q0 >> wbit) & 1ull) + (int)((q1 >> wbit) & 1ull)
              + (int)((m2b[(size_t)k * 4] >> hb) & 1ull)
              + (int)((m3b[(size_t)k * 4] >> hb) & 1ull);
        float fV = (float)v;
        sv[k] = fV / (fV + 1e-6f);
    }
    f32x4 xv = reinterpret_cast<const f32x4*>(x)[i];
    f32x4 ov = xv * sv;
    __builtin_nontemporal_store(ov, reinterpret_cast<f32x4*>(out) + i);
}

extern "C" void kernel_launch(void* const* d_in, const int* in_sizes, int n_in,
                              void* d_out, int out_size, void* d_ws, size_t ws_size,
                              hipStream_t stream) {
    const float* x = (const float*)d_in[0];
    float* out = (float*)d_out;
    char* ws = (char*)d_ws;

    float* m     = (float*)(ws);                                    // 2 MB
    float* mag   = (float*)(ws + (size_t)2 * 1024 * 1024);          // 2 MB
    signed char* adj = (signed char*)(ws + (size_t)4 * 1024 * 1024);        // 512 KB
    u64* masks   = (u64*)(ws + (size_t)4 * 1024 * 1024 + 524288);           // 256 KB
    float* part  = (float*)(ws + (size_t)4 * 1024 * 1024 + 524288 + 262144);// 16 KB
    unsigned* mn_u = (unsigned*)(ws + (size_t)4 * 1024 * 1024 + 524288 + 262144 + 16384);
    unsigned* mx_u = mn_u + 8;

    k_mean<<<BB * 256, 256, 0, stream>>>(x, m, mn_u, mx_u);
    k_sobel<<<BB * HH, 256, 0, stream>>>(m, mag, mn_u, mx_u);
    k_adjpart<<<BB * HH, 256, 0, stream>>>(mag, mn_u, mx_u, adj, part);
    k_travbase<<<32, 256, 0, stream>>>(adj, part, masks);
    k_out<<<(BB * CC * HW / 4) / 256, 256, 0, stream>>>(x, masks, out);
}

// Round 7
// 168.076 us; speedup vs baseline: 2.0267x; 1.7998x over previous
//
#include <hip/hip_runtime.h>
#include <math.h>

#define BB 8
#define CC 96
#define HH 256
#define WW 256
#define HW (HH*WW)

typedef unsigned long long u64;
typedef float f32x4 __attribute__((ext_vector_type(4)));
typedef u64 u64x2 __attribute__((ext_vector_type(2)));

// ---------------- channel mean: x[B,C,H,W] -> m[B,H,W]  (+ init min/max) ----------------
__global__ void k_mean(const float* __restrict__ x, float* __restrict__ m,
                       unsigned* __restrict__ mn_u, unsigned* __restrict__ mx_u) {
    if (blockIdx.x == 0 && threadIdx.x < 2 * BB) {
        if (threadIdx.x < BB) mn_u[threadIdx.x] = 0x7f800000u;
        else                  mx_u[threadIdx.x - BB] = 0u;
    }
    int blk = blockIdx.x;                 // b*256 + tile
    int b = blk >> 8, tile = blk & 255;
    int wv = threadIdx.x >> 6, ln = threadIdx.x & 63;
    int hw4 = tile * 64 + ln;             // float4 index within image
    const int per = HW / 4;               // 16384
    const float4* xb = reinterpret_cast<const float4*>(x)
                     + ((size_t)b * CC + wv * 24) * per + hw4;
    double a0 = 0, a1 = 0, a2 = 0, a3 = 0;
#pragma unroll
    for (int c = 0; c < 24; ++c) {
        float4 v = xb[(size_t)c * per];
        a0 += (double)v.x; a1 += (double)v.y; a2 += (double)v.z; a3 += (double)v.w;
    }
    __shared__ double sbuf[4][4][64];
    sbuf[wv][0][ln] = a0; sbuf[wv][1][ln] = a1;
    sbuf[wv][2][ln] = a2; sbuf[wv][3][ln] = a3;
    __syncthreads();
    if (wv == 0) {
        double r0 = sbuf[0][0][ln] + sbuf[1][0][ln] + sbuf[2][0][ln] + sbuf[3][0][ln];
        double r1 = sbuf[0][1][ln] + sbuf[1][1][ln] + sbuf[2][1][ln] + sbuf[3][1][ln];
        double r2 = sbuf[0][2][ln] + sbuf[1][2][ln] + sbuf[2][2][ln] + sbuf[3][2][ln];
        double r3 = sbuf[0][3][ln] + sbuf[1][3][ln] + sbuf[2][3][ln] + sbuf[3][3][ln];
        float4 o;
        o.x = (float)(r0 / 96.0); o.y = (float)(r1 / 96.0);
        o.z = (float)(r2 / 96.0); o.w = (float)(r3 / 96.0);
        reinterpret_cast<float4*>(m)[(size_t)b * per + hw4] = o;
    }
}

// ---------------- sobel magnitude + per-image min/max ----------------
__global__ void k_sobel(const float* __restrict__ m, float* __restrict__ mag,
                        unsigned* mn_u, unsigned* mx_u) {
    int row = blockIdx.x;            // b*HH + h  (one row per block)
    int b = row >> 8, h = row & 255, w = threadIdx.x;
    const float* mb = m + (size_t)b * HW;
    auto at = [&](int hh, int ww) -> float {
        if (hh < 0 || hh >= HH || ww < 0 || ww >= WW) return 0.0f;
        return mb[hh * WW + ww];
    };
    float a00 = at(h - 1, w - 1), a01 = at(h - 1, w), a02 = at(h - 1, w + 1);
    float a10 = at(h, w - 1),                         a12 = at(h, w + 1);
    float a20 = at(h + 1, w - 1), a21 = at(h + 1, w), a22 = at(h + 1, w + 1);
    float gx = a00 - a02 + 2.0f * a10 - 2.0f * a12 + a20 - a22;
    float gy = a00 + 2.0f * a01 + a02 - a20 - 2.0f * a21 - a22;
    float mg = sqrtf(gx * gx + gy * gy + 1e-6f);
    mag[row * WW + w] = mg;

    float lmn = mg, lmx = mg;
    for (int off = 32; off; off >>= 1) {
        lmn = fminf(lmn, __shfl_down(lmn, off));
        lmx = fmaxf(lmx, __shfl_down(lmx, off));
    }
    __shared__ float smn[4], smx[4];
    int wv = threadIdx.x >> 6, ln = threadIdx.x & 63;
    if (ln == 0) { smn[wv] = lmn; smx[wv] = lmx; }
    __syncthreads();
    if (threadIdx.x == 0) {
        float bmn = fminf(fminf(smn[0], smn[1]), fminf(smn[2], smn[3]));
        float bmx = fmaxf(fmaxf(smx[0], smx[1]), fmaxf(smx[2], smx[3]));
        atomicMin(&mn_u[b], __float_as_uint(bmn));   // mg > 0 -> uint order == float order
        atomicMax(&mx_u[b], __float_as_uint(bmx));
    }
}

// ---------------- fused: normalize (recompute per neighbor) -> adj + part ----------------
__global__ void k_adjpart(const float* __restrict__ mag, const unsigned* __restrict__ mn_u,
                          const unsigned* __restrict__ mx_u, signed char* __restrict__ adj,
                          float* __restrict__ part) {
    int row = blockIdx.x;            // b*HH + h
    int b = row >> 8, h = row & 255, w = threadIdx.x;
    float mn = __uint_as_float(mn_u[b]);
    float mx = __uint_as_float(mx_u[b]);
    float rng = mx - mn;
    const float* gb = mag + (size_t)b * HW;
    auto cat = [&](int hh, int ww) -> float {
        if (hh < 0 || hh >= HH || ww < 0 || ww >= WW) return 0.0f;
        float mg = gb[hh * WW + ww];
        return (rng > 0.0f) ? (mg - mn) / (rng + 1e-6f) : 0.0f;
    };
    float cc = cat(h, w);

    float r = cc;
    for (int off = 32; off; off >>= 1) r += __shfl_down(r, off);
    __shared__ float s[4];
    int wv = threadIdx.x >> 6, ln = threadIdx.x & 63;
    if (ln == 0) s[wv] = r;
    __syncthreads();
    if (threadIdx.x == 0) {
        part[row * 2 + 0] = s[0] + s[1];   // w in [0,128)
        part[row * 2 + 1] = s[2] + s[3];   // w in [128,256)
    }

    const float w9 = 1.0f / 9.0f;
    float acc = 0.0f;
    acc = fmaf(cat(h - 1, w - 1), w9, acc);
    acc = fmaf(cat(h - 1, w    ), w9, acc);
    acc = fmaf(cat(h - 1, w + 1), w9, acc);
    acc = fmaf(cat(h    , w - 1), w9, acc);
    acc = fmaf(cc,               w9, acc);
    acc = fmaf(cat(h    , w + 1), w9, acc);
    acc = fmaf(cat(h + 1, w - 1), w9, acc);
    acc = fmaf(cat(h + 1, w    ), w9, acc);
    acc = fmaf(cat(h + 1, w + 1), w9, acc);
    float sg = 1.0f / (1.0f + expf(-5.0f * (acc - 0.5f)));
    adj[row * WW + w] = (signed char)(int)rintf(sg * 2.0f - 1.0f);
}

// ---------------- fused base + traversal -> row-layout masks + transposed col masks ----------------
#define SETBIT(j) do { int _j = (j); \
    if (_j < 64) m0 |= 1ull << _j; \
    else if (_j < 128) m1 |= 1ull << (_j - 64); \
    else if (_j < 192) m2 |= 1ull << (_j - 128); \
    else m3 |= 1ull << (_j - 192); } while (0)

__global__ void k_travbase(const signed char* __restrict__ adj, const float* __restrict__ part,
                           u64* __restrict__ masks, u64* __restrict__ colm) {
    int blk = blockIdx.x;                 // 0..31, = dir*8 + b
    int dir = blk >> 3, b = blk & 7;
    int t = threadIdx.x;

    __shared__ double sd[128];
    __shared__ int sbs;
    int hlo = (dir >> 1) ? 128 : 0;
    int col = dir & 1;
    if (t < 128) sd[t] = (double)part[((b << 8) + hlo + t) * 2 + col];
    __syncthreads();
    for (int str = 64; str > 0; str >>= 1) {
        if (t < str) sd[t] += sd[t + str];
        __syncthreads();
    }
    if (t == 0) {
        float rc = (float)(sd[0] / 16384.0);
        float sig = 1.0f / (1.0f + expf(-5.0f * (rc - 0.5f)));
        float bsf = 5.0f - sig * 4.0f;
        bsf = fminf(fmaxf(bsf, 1.0f), 5.0f);
        sbs = (int)rintf(bsf);
    }
    __syncthreads();
    int bs = sbs;

    int r = t;
    const signed char* ab = adj + (size_t)b * HW;
    u64 m0 = 0, m1 = 0, m2 = 0, m3 = 0;
    if (dir == 0) {
        int j = 0;
        while (j < WW) { SETBIT(j);
            int st = bs + (int)ab[r * WW + j];
            st = st < 1 ? 1 : (st > 5 ? 5 : st); j += st; }
    } else if (dir == 1) {
        int j = WW - 1;
        while (j >= 0) { SETBIT(j);
            int st = bs + (int)ab[r * WW + j];
            st = st < 1 ? 1 : (st > 5 ? 5 : st); j -= st; }
    } else if (dir == 2) {
        int j = 0;
        while (j < HH) { SETBIT(j);
            int st = bs + (int)ab[j * WW + r];
            st = st < 1 ? 1 : (st > 5 ? 5 : st); j += st; }
    } else {
        int j = HH - 1;
        while (j >= 0) { SETBIT(j);
            int st = bs + (int)ab[j * WW + r];
            st = st < 1 ? 1 : (st > 5 ? 5 : st); j -= st; }
    }
    if (dir < 2) {
        u64* o = masks + (((size_t)dir * BB + b) * 256 + r) * 4;
        o[0] = m0; o[1] = m1; o[2] = m2; o[3] = m3;
    } else {
        // transposed: colm[(dir-2)][b][hwd][w] ; lane = w -> coalesced stores
        u64* ct = colm + (((size_t)(dir - 2) * BB + b) * 4) * 256 + r;
        ct[0 * 256] = m0; ct[1 * 256] = m1; ct[2 * 256] = m2; ct[3 * 256] = m3;
    }
}

// ---------------- output: out = x * V/(V+eps), all mask reads coalesced ----------------
__global__ void k_out(const float* __restrict__ x, const u64* __restrict__ masks,
                      const u64* __restrict__ colm, float* __restrict__ out) {
    const int per_img4 = CC * HW / 4;     // 1572864
    const int hw4n = HW / 4;              // 16384 (pow2)
    int i = blockIdx.x * blockDim.x + threadIdx.x;   // exact cover of total4
    int b = i / per_img4;
    int hw4 = i & (hw4n - 1);
    int h = hw4 >> 6;                     // hw4 = h*64 + w4
    int w0 = (hw4 & 63) << 2;             // first of 4 consecutive w (4-aligned)
    int hb = h & 63, hwd = h >> 6;

    // row-direction masks: one word covers w0..w0+3 (broadcast across 16 lanes)
    u64 q0 = masks[(((size_t)0 * BB + b) * 256 + h) * 4 + (w0 >> 6)];
    u64 q1 = masks[(((size_t)1 * BB + b) * 256 + h) * 4 + (w0 >> 6)];
    // col-direction masks: transposed layout -> 4 consecutive u64, unit-stride across lanes
    const u64* c2 = colm + (((size_t)0 * BB + b) * 4 + hwd) * 256 + w0;
    const u64* c3 = colm + (((size_t)1 * BB + b) * 4 + hwd) * 256 + w0;
    u64x2 c2a = *reinterpret_cast<const u64x2*>(c2);
    u64x2 c2b = *reinterpret_cast<const u64x2*>(c2 + 2);
    u64x2 c3a = *reinterpret_cast<const u64x2*>(c3);
    u64x2 c3b = *reinterpret_cast<const u64x2*>(c3 + 2);
    u64 cw2[4] = { c2a.x, c2a.y, c2b.x, c2b.y };
    u64 cw3[4] = { c3a.x, c3a.y, c3b.x, c3b.y };

    f32x4 sv;
#pragma unroll
    for (int k = 0; k < 4; ++k) {
        int wbit = (w0 & 63) + k;
        int v = (int)((q0 >> wbit) & 1ull) + (int)((q1 >> wbit) & 1ull)
              + (int)((cw2[k] >> hb) & 1ull) + (int)((cw3[k] >> hb) & 1ull);
        float fV = (float)v;
        sv[k] = fV / (fV + 1e-6f);
    }
    f32x4 xv = reinterpret_cast<const f32x4*>(x)[i];
    f32x4 ov = xv * sv;
    __builtin_nontemporal_store(ov, reinterpret_cast<f32x4*>(out) + i);
}

extern "C" void kernel_launch(void* const* d_in, const int* in_sizes, int n_in,
                              void* d_out, int out_size, void* d_ws, size_t ws_size,
                              hipStream_t stream) {
    const float* x = (const float*)d_in[0];
    float* out = (float*)d_out;
    char* ws = (char*)d_ws;

    // workspace layout — sizes: masks 2*8*256*4*8 = 128 KB, colm 2*8*4*256*8 = 128 KB
    size_t off = 0;
    float* m     = (float*)(ws + off); off += (size_t)2 * 1024 * 1024;      // 2 MB
    float* mag   = (float*)(ws + off); off += (size_t)2 * 1024 * 1024;      // 2 MB
    signed char* adj = (signed char*)(ws + off); off += 524288;             // 512 KB
    u64* masks   = (u64*)(ws + off); off += 131072;                         // 128 KB (dirs 0,1)
    u64* colm    = (u64*)(ws + off); off += 131072;                         // 128 KB (dirs 2,3 transposed)
    float* part  = (float*)(ws + off); off += 16384;                        // 16 KB
    unsigned* mn_u = (unsigned*)(ws + off);
    unsigned* mx_u = mn_u + 8;

    k_mean<<<BB * 256, 256, 0, stream>>>(x, m, mn_u, mx_u);
    k_sobel<<<BB * HH, 256, 0, stream>>>(m, mag, mn_u, mx_u);
    k_adjpart<<<BB * HH, 256, 0, stream>>>(mag, mn_u, mx_u, adj, part);
    k_travbase<<<32, 256, 0, stream>>>(adj, part, masks, colm);
    k_out<<<(BB * CC * HW / 4) / 256, 256, 0, stream>>>(x, masks, colm, out);
}